// Round 1
// baseline (1701.138 us; speedup 1.0000x reference)
//
#include <hip/hip_runtime.h>
#include <cmath>

typedef unsigned short u16;
typedef __bf16 bf16x8 __attribute__((ext_vector_type(8)));
typedef float f32x4 __attribute__((ext_vector_type(4)));
typedef u16 u16x4 __attribute__((ext_vector_type(4)));

#define GLOAD16(g, l) __builtin_amdgcn_global_load_lds( \
    (const __attribute__((address_space(1))) unsigned int*)(g), \
    (__attribute__((address_space(3))) unsigned int*)(l), 16, 0, 0)

__device__ __forceinline__ u16 f2b(float f) {
  unsigned u = __builtin_bit_cast(unsigned, f);
  unsigned r = (u + 0x7fffu + ((u >> 16) & 1u)) >> 16;
  return (u16)r;
}

// ---------------- transpose + f32->bf16 convert:  W[K][N] f32 -> Wt[N][Kp] bf16 (zero-pad K..Kp)
__global__ __launch_bounds__(256)
void transw_k(const float* __restrict__ W, u16* __restrict__ Wt,
              int K, int N, int Kp, long sIn, long sOut)
{
  __shared__ float t[32][33];
  int n0 = blockIdx.x * 32, k0 = blockIdx.y * 32, l = blockIdx.z;
  const float* Wl = W + (long)l * sIn;
  u16* Wo = Wt + (long)l * sOut;
  int tx = threadIdx.x & 31, ty = threadIdx.x >> 5;
  #pragma unroll
  for (int i = 0; i < 4; ++i) {
    int k = k0 + ty + i * 8;
    t[ty + i * 8][tx] = (k < K) ? Wl[(long)k * N + n0 + tx] : 0.0f;
  }
  __syncthreads();
  #pragma unroll
  for (int i = 0; i < 4; ++i) {
    int n = n0 + ty + i * 8;
    Wo[(long)n * Kp + k0 + tx] = f2b(t[tx][ty + i * 8]);
  }
}

// ---------------- concat qkv biases: out[12][2304]
__global__ void biascat_k(const float* bq0, const float* bk0, const float* bv0,
                          const float* bq1, const float* bk1, const float* bv1, float* o)
{
  int idx = blockIdx.x * 256 + threadIdx.x;            // 12*2304
  int c = idx % 2304, l = idx / 2304;
  int st = l / 6, li = l % 6;
  const float* src = (c < 768) ? (st ? bq1 : bq0) : (c < 1536) ? (st ? bk1 : bk0) : (st ? bv1 : bv0);
  o[idx] = src[li * 768 + (c % 768)];
}

// ---------------- cond f32 [512][438] -> bf16 [512][448] zero-padded
__global__ void condcvt_k(const float* __restrict__ c, u16* __restrict__ o)
{
  int idx = blockIdx.x * 256 + threadIdx.x;            // 512*448
  int k = idx % 448, r = idx / 448;
  o[idx] = f2b(k < 438 ? c[r * 438 + k] : 0.0f);
}

// ---------------- token embeddings + pos_emb for streams 1,2 -> x f32
__global__ void embed_k(const int* __restrict__ iu, const int* __restrict__ idn,
                        const float* __restrict__ teu, const float* __restrict__ ted,
                        const float* __restrict__ pe, float* __restrict__ x)
{
  int idx = blockIdx.x * 256 + threadIdx.x;            // 2*512*192
  int c4 = idx % 192; int rest = idx / 192;
  int tt = rest % 512; int b = rest / 512;
  int i = tt & 255; int s = tt >> 8;
  int tok = s ? idn[b * 256 + i] : iu[b * 256 + i];
  const float4* src = (const float4*)(s ? (ted + (long)tok * 768) : (teu + (long)tok * 768));
  int prow = 256 + s * 256 + i;
  float4 pv = ((const float4*)(pe + (long)prow * 768))[c4];
  float4 sv = src[c4];
  float4 ov; ov.x = sv.x + pv.x; ov.y = sv.y + pv.y; ov.z = sv.z + pv.z; ov.w = sv.w + pv.w;
  ((float4*)(x + ((long)b * 768 + prow) * 768))[c4] = ov;
}

// ---------------- LayerNorm f32 in -> bf16 out, C=768, wave per row
__global__ __launch_bounds__(256)
void ln_k(const float* __restrict__ x, const float* __restrict__ gg,
          const float* __restrict__ bb, u16* __restrict__ out)
{
  int row = blockIdx.x * 4 + (threadIdx.x >> 6);
  int lane = threadIdx.x & 63;
  const float* xr = x + (long)row * 768;
  float v[12]; float s = 0.0f;
  #pragma unroll
  for (int j = 0; j < 12; ++j) { v[j] = xr[lane + 64 * j]; s += v[j]; }
  #pragma unroll
  for (int d = 1; d < 64; d <<= 1) s += __shfl_xor(s, d);
  float mean = s * (1.0f / 768.0f);
  float s2 = 0.0f;
  #pragma unroll
  for (int j = 0; j < 12; ++j) { float d = v[j] - mean; s2 += d * d; }
  #pragma unroll
  for (int d = 1; d < 64; d <<= 1) s2 += __shfl_xor(s2, d);
  float rstd = rsqrtf(s2 * (1.0f / 768.0f) + 1e-5f);
  u16* orow = out + (long)row * 768;
  #pragma unroll
  for (int j = 0; j < 12; ++j) {
    int c = lane + 64 * j;
    orow[c] = f2b((v[j] - mean) * rstd * gg[c] + bb[c]);
  }
}

// ---------------- GEMM: C[M,N] = A[M,K](bf16) @ Bt[N,K](bf16)^T, 64x64 tile, BK=64
#define EPI_PLAIN 0
#define EPI_PE    1
#define EPI_QKV   2
#define EPI_RES   3
#define EPI_GELU  4

template<int EPI, bool BIAS>
__global__ __launch_bounds__(256)
void gemm_k(const u16* __restrict__ A, const u16* __restrict__ Bt, const float* __restrict__ bias,
            float* outf, u16* outb, u16* qb, u16* kb, u16* vT, const float* aux,
            int M, int N, int K, int lda, int ldc,
            int astr, int aoff, int cstr, int coff)
{
  __shared__ alignas(16) u16 Al[64 * 64];
  __shared__ alignas(16) u16 Bl[64 * 64];
  const int tid = threadIdx.x;
  const int m0 = blockIdx.x * 64, n0 = blockIdx.y * 64;
  const int lane = tid & 63, w = tid >> 6, l15 = lane & 15, g = lane >> 4;
  const int wm = (w >> 1) * 32, wn = (w & 1) * 32;

  // staging: rows of 64 bf16 (128B, 8 slots of 16B); stored[row][s] = data[row][s^(row&7)]
  const int i0 = tid, i1 = tid + 256;
  const int r0 = i0 >> 3, r1 = i1 >> 3;
  const int s0i = ((i0 & 7) ^ (r0 & 7)) * 8, s1i = ((i1 & 7) ^ (r1 & 7)) * 8;
  const int am0 = m0 + r0, am1 = m0 + r1;
  const u16* ap0 = A + (long)((am0 >> 8) * astr + aoff + (am0 & 255)) * lda + s0i;
  const u16* ap1 = A + (long)((am1 >> 8) * astr + aoff + (am1 & 255)) * lda + s1i;
  const u16* bp0 = Bt + (long)(n0 + r0) * K + s0i;
  const u16* bp1 = Bt + (long)(n0 + r1) * K + s1i;
  u16* ald0 = &Al[(i0 >> 6) * 512]; u16* ald1 = &Al[(i1 >> 6) * 512];
  u16* bld0 = &Bl[(i0 >> 6) * 512]; u16* bld1 = &Bl[(i1 >> 6) * 512];

  const int ra0 = wm + l15, ra1 = ra0 + 16, rb0 = wn + l15, rb1 = rb0 + 16;
  int offA0[2], offA1[2], offB0[2], offB1[2];
  #pragma unroll
  for (int ks = 0; ks < 2; ++ks) {
    int so = 4 * ks + g;
    offA0[ks] = ra0 * 128 + ((so ^ (ra0 & 7)) << 4);
    offA1[ks] = ra1 * 128 + ((so ^ (ra1 & 7)) << 4);
    offB0[ks] = rb0 * 128 + ((so ^ (rb0 & 7)) << 4);
    offB1[ks] = rb1 * 128 + ((so ^ (rb1 & 7)) << 4);
  }

  f32x4 ac00{}, ac01{}, ac10{}, ac11{};
  for (int kt = 0; kt < K; kt += 64) {
    __syncthreads();
    GLOAD16(ap0 + kt, ald0);
    GLOAD16(ap1 + kt, ald1);
    GLOAD16(bp0 + kt, bld0);
    GLOAD16(bp1 + kt, bld1);
    __syncthreads();
    #pragma unroll
    for (int ks = 0; ks < 2; ++ks) {
      bf16x8 a0 = *(const bf16x8*)((const char*)Al + offA0[ks]);
      bf16x8 a1 = *(const bf16x8*)((const char*)Al + offA1[ks]);
      bf16x8 b0 = *(const bf16x8*)((const char*)Bl + offB0[ks]);
      bf16x8 b1 = *(const bf16x8*)((const char*)Bl + offB1[ks]);
      ac00 = __builtin_amdgcn_mfma_f32_16x16x32_bf16(a0, b0, ac00, 0, 0, 0);
      ac01 = __builtin_amdgcn_mfma_f32_16x16x32_bf16(a0, b1, ac01, 0, 0, 0);
      ac10 = __builtin_amdgcn_mfma_f32_16x16x32_bf16(a1, b0, ac10, 0, 0, 0);
      ac11 = __builtin_amdgcn_mfma_f32_16x16x32_bf16(a1, b1, ac11, 0, 0, 0);
    }
  }

  #pragma unroll
  for (int mi = 0; mi < 2; ++mi)
  #pragma unroll
  for (int ni = 0; ni < 2; ++ni) {
    f32x4 a = (mi == 0) ? ((ni == 0) ? ac00 : ac01) : ((ni == 0) ? ac10 : ac11);
    int col = n0 + wn + 16 * ni + l15;
    float bv = BIAS ? bias[col] : 0.0f;
    int mlb = m0 + wm + 16 * mi + 4 * g;   // row of r=0 (D row = 4*(lane>>4)+r)
    if (EPI == EPI_QKV) {
      if (col >= 1536) {
        int c2 = col - 1536, hh = c2 >> 6, dd = c2 & 63;
        int bb2 = mlb >= 768 ? 1 : 0;
        int t0 = mlb - bb2 * 768;
        u16x4 pk;
        #pragma unroll
        for (int r = 0; r < 4; ++r) pk[r] = f2b(a[r] + bv);
        *(u16x4*)(vT + (long)((bb2 * 12 + hh) * 64 + dd) * 768 + t0) = pk;
      } else {
        u16* dst = (col < 768) ? (qb + (long)mlb * 768 + col) : (kb + (long)mlb * 768 + (col - 768));
        #pragma unroll
        for (int r = 0; r < 4; ++r) dst[(long)r * 768] = f2b(a[r] + bv);
      }
    } else {
      #pragma unroll
      for (int r = 0; r < 4; ++r) {
        int rg = mlb + r;
        long crow = (long)(rg >> 8) * cstr + coff + (rg & 255);
        float v = a[r] + bv;
        if (EPI == EPI_PLAIN)      outf[crow * ldc + col] = v;
        else if (EPI == EPI_PE)    outf[crow * ldc + col] = v + aux[(long)(rg & 255) * 768 + col];
        else if (EPI == EPI_RES)   outf[crow * ldc + col] = v + aux[crow * ldc + col];
        else if (EPI == EPI_GELU)  outb[crow * ldc + col] = f2b(0.5f * v * (1.0f + erff(v * 0.70710678f)));
      }
    }
  }
}

// ---------------- flash attention: 64 q-rows per WG, swapped QK^T, online softmax
#define MFMA_BF16 __builtin_amdgcn_mfma_f32_16x16x32_bf16
__global__ __launch_bounds__(256)
void attn_k(const u16* __restrict__ qb, const u16* __restrict__ kb,
            const u16* __restrict__ vT, u16* __restrict__ y)
{
  __shared__ alignas(16) u16 Kl[4096];        // [key 64][d 64] swizzled
  __shared__ alignas(16) u16 Vl[4096];        // [d 64][key 64] swizzled
  __shared__ alignas(16) u16 Pl[4][16 * 72];  // per-wave P[q 16][key 64] pad 72
  __shared__ float red[4][16];
  const int qt = blockIdx.x, bh = blockIdx.y;
  const int b = bh / 12, h = bh - b * 12;
  const int tid = threadIdx.x, w = tid >> 6, lane = tid & 63, l15 = lane & 15, g = lane >> 4;
  const int qrow = qt * 64 + w * 16 + l15;
  const int qm = qrow & 255;
  const u16* qp = qb + (long)(b * 768 + qrow) * 768 + h * 64;
  bf16x8 qf0 = *(const bf16x8*)(qp + 8 * g);
  bf16x8 qf1 = *(const bf16x8*)(qp + 32 + 8 * g);
  f32x4 O0{}, O1{}, O2{}, O3{};
  float m_run = -1e30f, l_run = 0.0f;

  const int i0 = tid, i1 = tid + 256;
  const int kr0 = i0 >> 3, kr1 = i1 >> 3;
  const int sl0 = ((i0 & 7) ^ (kr0 & 7)) * 8, sl1 = ((i1 & 7) ^ (kr1 & 7)) * 8;
  const u16* kp0 = kb + (long)(b * 768 + kr0) * 768 + h * 64 + sl0;
  const u16* kp1 = kb + (long)(b * 768 + kr1) * 768 + h * 64 + sl1;
  const u16* vp0 = vT + (long)(bh * 64 + kr0) * 768 + sl0;
  const u16* vp1 = vT + (long)(bh * 64 + kr1) * 768 + sl1;
  u16* kld0 = &Kl[(i0 >> 6) * 512]; u16* kld1 = &Kl[(i1 >> 6) * 512];
  u16* vld0 = &Vl[(i0 >> 6) * 512]; u16* vld1 = &Vl[(i1 >> 6) * 512];

  for (int kt = 0; kt < 12; ++kt) {
    __syncthreads();
    GLOAD16(kp0 + (long)kt * 64 * 768, kld0);
    GLOAD16(kp1 + (long)kt * 64 * 768, kld1);
    GLOAD16(vp0 + kt * 64, vld0);
    GLOAD16(vp1 + kt * 64, vld1);
    __syncthreads();

    f32x4 s0{}, s1{}, s2{}, s3{};
    #pragma unroll
    for (int ks = 0; ks < 2; ++ks) {
      bf16x8 qf = ks ? qf1 : qf0;
      int sb = ((4 * ks + g) ^ (l15 & 7)) << 4;
      bf16x8 k0 = *(const bf16x8*)((const char*)Kl + (0  + l15) * 128 + sb);
      bf16x8 k1 = *(const bf16x8*)((const char*)Kl + (16 + l15) * 128 + sb);
      bf16x8 k2 = *(const bf16x8*)((const char*)Kl + (32 + l15) * 128 + sb);
      bf16x8 k3 = *(const bf16x8*)((const char*)Kl + (48 + l15) * 128 + sb);
      s0 = MFMA_BF16(k0, qf, s0, 0, 0, 0);
      s1 = MFMA_BF16(k1, qf, s1, 0, 0, 0);
      s2 = MFMA_BF16(k2, qf, s2, 0, 0, 0);
      s3 = MFMA_BF16(k3, qf, s3, 0, 0, 0);
    }
    float sv[16]; float tm = -1e30f;
    #pragma unroll
    for (int mt = 0; mt < 4; ++mt) {
      f32x4 sm4 = (mt == 0) ? s0 : (mt == 1) ? s1 : (mt == 2) ? s2 : s3;
      #pragma unroll
      for (int r = 0; r < 4; ++r) {
        int kg = kt * 64 + mt * 16 + 4 * g + r;
        float val = ((kg & 255) <= qm) ? sm4[r] * 0.125f : -1e30f;
        sv[mt * 4 + r] = val; tm = fmaxf(tm, val);
      }
    }
    tm = fmaxf(tm, __shfl_xor(tm, 16));
    tm = fmaxf(tm, __shfl_xor(tm, 32));
    float mn = fmaxf(m_run, tm);
    float alpha = __expf(m_run - mn);
    float ps = 0.0f; u16 pb16[16];
    #pragma unroll
    for (int j = 0; j < 16; ++j) {
      float p = (sv[j] <= -1e29f) ? 0.0f : __expf(sv[j] - mn);
      ps += p; pb16[j] = f2b(p);
    }
    ps += __shfl_xor(ps, 16); ps += __shfl_xor(ps, 32);
    l_run = l_run * alpha + ps; m_run = mn;
    if (lane < 16) red[w][lane] = alpha;
    #pragma unroll
    for (int mt = 0; mt < 4; ++mt) {
      u16x4 pk; pk[0] = pb16[4*mt]; pk[1] = pb16[4*mt+1]; pk[2] = pb16[4*mt+2]; pk[3] = pb16[4*mt+3];
      *(u16x4*)((char*)&Pl[w][0] + l15 * 144 + mt * 32 + 8 * g) = pk;
    }
    __syncthreads();
    float a0 = red[w][4 * g], a1 = red[w][4 * g + 1], a2 = red[w][4 * g + 2], a3 = red[w][4 * g + 3];
    O0[0] *= a0; O0[1] *= a1; O0[2] *= a2; O0[3] *= a3;
    O1[0] *= a0; O1[1] *= a1; O1[2] *= a2; O1[3] *= a3;
    O2[0] *= a0; O2[1] *= a1; O2[2] *= a2; O2[3] *= a3;
    O3[0] *= a0; O3[1] *= a1; O3[2] *= a2; O3[3] *= a3;
    #pragma unroll
    for (int ks = 0; ks < 2; ++ks) {
      bf16x8 pf = *(const bf16x8*)((const char*)&Pl[w][0] + l15 * 144 + 64 * ks + 16 * g);
      int sb = ((4 * ks + g) ^ (l15 & 7)) << 4;
      bf16x8 v0 = *(const bf16x8*)((const char*)Vl + (0  + l15) * 128 + sb);
      bf16x8 v1 = *(const bf16x8*)((const char*)Vl + (16 + l15) * 128 + sb);
      bf16x8 v2 = *(const bf16x8*)((const char*)Vl + (32 + l15) * 128 + sb);
      bf16x8 v3 = *(const bf16x8*)((const char*)Vl + (48 + l15) * 128 + sb);
      O0 = MFMA_BF16(pf, v0, O0, 0, 0, 0);
      O1 = MFMA_BF16(pf, v1, O1, 0, 0, 0);
      O2 = MFMA_BF16(pf, v2, O2, 0, 0, 0);
      O3 = MFMA_BF16(pf, v3, O3, 0, 0, 0);
    }
  }
  if (lane < 16) red[w][lane] = l_run;
  __syncthreads();
  float n0i = 1.0f / red[w][4 * g], n1i = 1.0f / red[w][4 * g + 1];
  float n2i = 1.0f / red[w][4 * g + 2], n3i = 1.0f / red[w][4 * g + 3];
  long yr = (long)(b * 768 + qt * 64 + w * 16 + 4 * g);
  #pragma unroll
  for (int ni = 0; ni < 4; ++ni) {
    f32x4 Ov = (ni == 0) ? O0 : (ni == 1) ? O1 : (ni == 2) ? O2 : O3;
    int c = h * 64 + ni * 16 + l15;
    y[(yr + 0) * 768 + c] = f2b(Ov[0] * n0i);
    y[(yr + 1) * 768 + c] = f2b(Ov[1] * n1i);
    y[(yr + 2) * 768 + c] = f2b(Ov[2] * n2i);
    y[(yr + 3) * 768 + c] = f2b(Ov[3] * n3i);
  }
}

// ================= host =================
extern "C" void kernel_launch(void* const* d_in, const int* in_sizes, int n_in,
                              void* d_out, int out_size, void* d_ws, size_t ws_size,
                              hipStream_t stream)
{
  (void)in_sizes; (void)n_in; (void)out_size;
  auto F = [&](int i){ return (const float*)d_in[i]; };
  const int* idx_up = (const int*)d_in[0];
  const int* idx_dn = (const int*)d_in[1];
  const float* cond = F(2);
  const float* teu = F(3);
  const float* ted = F(4);
  const float* pe  = F(5);
  const float* cw  = F(6);
  const float* cb  = F(7);
  float* outp = (float*)d_out;
  char* ws = (char*)d_ws;

  size_t o = 0;
  auto take = [&](size_t bytes){ void* p = ws + o; o += bytes; return p; };
  float* x    = (float*)take(4718592);   // [1536][768] f32 residual stream
  u16*   h    = (u16*)take(2359296);     // LN out bf16
  u16*   qbuf = (u16*)take(2359296);
  u16*   kbuf = (u16*)take(2359296);
  u16*   vT   = (u16*)take(2359296);     // [24][64][768]
  u16*   y    = (u16*)take(2359296);
  u16*   fca  = (u16*)take(9437184);     // [1536][3072]
  u16*   xf   = (u16*)take(2359296);
  u16*   cbf  = (u16*)take(458752);      // cond bf16 [512][448]
  float* qkvb = (float*)take(110592);    // [12][2304]
  u16*   hut  = (u16*)take(786432);
  u16*   hdt  = (u16*)take(786432);
  u16*   cwt  = (u16*)take(688128);      // [768][448]
  const size_t WL = 14155776;            // per-layer transposed weights (bytes)
  bool up = (ws_size >= o + 12 * WL);
  size_t nsl = up ? 12 : 1;
  u16* qkvt = (u16*)(ws + o);
  u16* wot  = qkvt + nsl * 2304 * 768;
  u16* fct  = wot  + nsl * 768 * 768;
  u16* prt  = fct  + nsl * 3072 * 768;

  auto trans = [&](const float* src, u16* dst, int K, int N, int Kp, long sIn, long sOut, int nz){
    transw_k<<<dim3(N / 32, Kp / 32, nz), dim3(256), 0, stream>>>(src, dst, K, N, Kp, sIn, sOut);
  };

  if (up) {
    for (int s = 0; s < 2; ++s) {
      for (int p = 0; p < 3; ++p)
        trans(F(8 + 16*s + 2 + 2*p), qkvt + (size_t)s*6*2304*768 + (size_t)p*768*768,
              768, 768, 768, 768L*768, 2304L*768, 6);
      trans(F(8 + 16*s + 8),  wot + (size_t)s*6*768*768,  768, 768, 768, 768L*768, 768L*768, 6);
      trans(F(8 + 16*s + 12), fct + (size_t)s*6*3072*768, 768, 3072, 768, 768L*3072, 3072L*768, 6);
      trans(F(8 + 16*s + 14), prt + (size_t)s*6*768*3072, 3072, 768, 3072, 3072L*768, 768L*3072, 6);
    }
  }
  trans(F(42), hut, 768, 512, 768, 0, 0, 1);
  trans(F(43), hdt, 768, 512, 768, 0, 0, 1);
  trans(cw,    cwt, 438, 768, 448, 0, 0, 1);
  biascat_k<<<dim3(108), dim3(256), 0, stream>>>(F(11), F(13), F(15), F(27), F(29), F(31), qkvb);
  condcvt_k<<<dim3(896), dim3(256), 0, stream>>>(cond, cbf);
  embed_k<<<dim3(768), dim3(256), 0, stream>>>(idx_up, idx_dn, teu, ted, pe, x);
  // cond @ cond_w + cond_b + pos_emb -> x rows b*768 + (0..255)
  gemm_k<EPI_PE, true><<<dim3(8, 12), dim3(256), 0, stream>>>(cbf, cwt, cb,
      x, nullptr, nullptr, nullptr, nullptr, pe,
      512, 768, 448, 448, 768, 256, 0, 768, 0);

  for (int l = 0; l < 12; ++l) {
    int s = l / 6, li = l % 6;
    u16* qkvt_l = qkvt + (up ? (size_t)l : 0) * 2304 * 768;
    u16* wot_l  = wot  + (up ? (size_t)l : 0) * 768 * 768;
    u16* fct_l  = fct  + (up ? (size_t)l : 0) * 3072 * 768;
    u16* prt_l  = prt  + (up ? (size_t)l : 0) * 768 * 3072;
    if (!up) {
      for (int p = 0; p < 3; ++p)
        trans(F(8 + 16*s + 2 + 2*p) + (size_t)li*768*768, qkvt_l + (size_t)p*768*768, 768, 768, 768, 0, 0, 1);
      trans(F(8 + 16*s + 8)  + (size_t)li*768*768,  wot_l, 768, 768, 768, 0, 0, 1);
      trans(F(8 + 16*s + 12) + (size_t)li*768*3072, fct_l, 768, 3072, 768, 0, 0, 1);
      trans(F(8 + 16*s + 14) + (size_t)li*3072*768, prt_l, 3072, 768, 3072, 0, 0, 1);
    }
    ln_k<<<dim3(384), dim3(256), 0, stream>>>(x, F(8+16*s+0) + (size_t)li*768, F(8+16*s+1) + (size_t)li*768, h);
    gemm_k<EPI_QKV, true><<<dim3(24, 36), dim3(256), 0, stream>>>(h, qkvt_l, qkvb + (size_t)l*2304,
        nullptr, nullptr, qbuf, kbuf, vT, nullptr,
        1536, 2304, 768, 768, 768, 256, 0, 256, 0);
    attn_k<<<dim3(12, 24), dim3(256), 0, stream>>>(qbuf, kbuf, vT, y);
    gemm_k<EPI_RES, true><<<dim3(24, 12), dim3(256), 0, stream>>>(y, wot_l, F(8+16*s+9) + (size_t)li*768,
        x, nullptr, nullptr, nullptr, nullptr, x,
        1536, 768, 768, 768, 768, 256, 0, 256, 0);
    ln_k<<<dim3(384), dim3(256), 0, stream>>>(x, F(8+16*s+10) + (size_t)li*768, F(8+16*s+11) + (size_t)li*768, h);
    gemm_k<EPI_GELU, true><<<dim3(24, 48), dim3(256), 0, stream>>>(h, fct_l, F(8+16*s+13) + (size_t)li*3072,
        nullptr, fca, nullptr, nullptr, nullptr, nullptr,
        1536, 3072, 768, 768, 3072, 256, 0, 256, 0);
    gemm_k<EPI_RES, true><<<dim3(24, 12), dim3(256), 0, stream>>>(fca, prt_l, F(8+16*s+15) + (size_t)li*768,
        x, nullptr, nullptr, nullptr, nullptr, x,
        1536, 768, 3072, 3072, 768, 256, 0, 256, 0);
  }
  ln_k<<<dim3(384), dim3(256), 0, stream>>>(x, F(40), F(41), xf);
  gemm_k<EPI_PLAIN, false><<<dim3(8, 8), dim3(256), 0, stream>>>(xf, hut, nullptr,
      outp, nullptr, nullptr, nullptr, nullptr, nullptr,
      512, 512, 768, 768, 512, 768, 256, 256, 0);
  gemm_k<EPI_PLAIN, false><<<dim3(8, 8), dim3(256), 0, stream>>>(xf, hdt, nullptr,
      outp + 262144, nullptr, nullptr, nullptr, nullptr, nullptr,
      512, 512, 768, 768, 512, 768, 512, 256, 0);
}